// Round 6
// baseline (48.436 us; speedup 1.0000x reference)
//
#include <hip/hip_runtime.h>
#include <math.h>

// LearnedDRoPEEnergy: B=16, K=256, H=W=64, T=1.0
#define NPOS 65536              // B*H*W

// 8 representative offsets (other 8 are negatives; d and gate symmetric,
// torus sum translation-invariant -> multiply by 2). Verified R1/R2/R4/R5.
__device__ __constant__ int c_dy8[8] = {-1, 0, -1, -1, -2,  0, -2, -2};
__device__ __constant__ int c_dx8[8] = { 0,-1, -1,  1,  0, -2, -2,  2};

// Kernel A: pack. Block (b, word, quarter): owns ALL 32 bits of `word` for
// 1024 positions. Loads: 32 planes x 4KB fully-sequential float4 runs
// (R4's good load pattern). Stores: one uint4 per thread, fully coalesced
// word-major (R5's good store pattern). No sub-dword scatter anywhere.
__global__ __launch_bounds__(256) void pack_kernel(const float* __restrict__ z,
                                                   unsigned* __restrict__ packw,
                                                   float* __restrict__ out) {
    int tid = threadIdx.x;
    unsigned beta = blockIdx.x;          // 0..511
    int b    = beta >> 5;                // 16
    int word = (beta >> 2) & 7;          // 8
    int q    = beta & 3;                 // 4 quarter-planes (1024 floats each)
    const float* base = z + ((size_t)(b * 256 + word * 32) << 12) + q * 1024 + tid * 4;
    unsigned a0 = 0, a1 = 0, a2 = 0, a3 = 0;
#pragma unroll
    for (int j = 0; j < 32; ++j) {
        const float* p = base + ((size_t)j << 12);
        float4 v = *(const float4*)p;    // 4KB sequential run per plane per block
        unsigned bit = 1u << j;
        if (v.x != 0.0f) a0 |= bit;
        if (v.y != 0.0f) a1 |= bit;
        if (v.z != 0.0f) a2 |= bit;
        if (v.w != 0.0f) a3 |= bit;
    }
    // word-major: packw[word][pos], pos = b*4096 + q*1024 + tid*4 .. +3
    unsigned idx = word * NPOS + (b << 12) + (q << 10) + (tid << 2);
    *(uint4*)(packw + idx) = make_uint4(a0, a1, a2, a3);   // 16B coalesced
    if (beta == 0 && tid < 16) out[tid] = 0.0f;
}

// Kernel B: one thread per (position, offset) pair. 2048 blocks x 256.
// In-kernel LUT build (R1-proven, ~400cyc), word-major coalesced pack loads,
// 32 byte-LUT LDS gathers, gate, block-reduce, one atomic, x2 symmetry.
__global__ __launch_bounds__(256) void energy_kernel(const unsigned* __restrict__ pw,
                                                     const float* __restrict__ w_logit,
                                                     const float* __restrict__ tau_p,
                                                     float* __restrict__ out) {
    __shared__ float wtab[32 * 256];     // 32 KB
    __shared__ float red[4];
    int tid = threadIdx.x;

    {   // build LUT: thread covers (p = tid>>3, v = (tid&7)*32 .. +31)
        int p = tid >> 3;
        int vbase = (tid & 7) * 32;
        float wv[8];
#pragma unroll
        for (int j = 0; j < 8; ++j) {
            float x = w_logit[p * 8 + j];
            wv[j] = log1pf(expf(x));     // softplus, fp32
        }
        for (int v = vbase; v < vbase + 32; ++v) {
            float s = 0.0f;
#pragma unroll
            for (int j = 0; j < 8; ++j) s += ((v >> j) & 1) ? wv[j] : 0.0f;
            wtab[p * 256 + v] = s;
        }
    }
    __syncthreads();

    float tau = tau_p[0];
    int t   = blockIdx.x * 256 + tid;    // 0 .. 524287
    int o   = t >> 16;                   // 0..7, uniform per block
    int pos = t & 65535;
    int b = pos >> 12;
    int h = (pos >> 6) & 63;
    int w = pos & 63;

    int h2 = (h + c_dy8[o]) & 63;
    int w2 = (w + c_dx8[o]) & 63;
    int np = (b << 12) | (h2 << 6) | w2;

    unsigned x[8];
#pragma unroll
    for (int wd = 0; wd < 8; ++wd) {
        unsigned c = pw[wd * NPOS + pos];   // coalesced, L2-resident (2MB)
        unsigned n = pw[wd * NPOS + np];    // coalesced shifted run
        x[wd] = c ^ n;
    }

    float d0 = 0.0f, d1 = 0.0f;
#pragma unroll
    for (int i = 0; i < 8; ++i) {
        unsigned xi = x[i];
        d0 += wtab[(i * 4 + 0) * 256 + (xi & 255)];
        d1 += wtab[(i * 4 + 1) * 256 + ((xi >> 8) & 255)];
        d0 += wtab[(i * 4 + 2) * 256 + ((xi >> 16) & 255)];
        d1 += wtab[(i * 4 + 3) * 256 + (xi >> 24)];
    }
    float d = d0 + d1;
    // gate*d = d / (1 + exp(d - tau)); exp overflow -> inf -> 0, correct limit
    float e = d / (1.0f + expf(d - tau));

#pragma unroll
    for (int s = 32; s > 0; s >>= 1) e += __shfl_down(e, s, 64);
    int lane = tid & 63, wv = tid >> 6;
    if (lane == 0) red[wv] = e;
    __syncthreads();
    if (tid == 0) atomicAdd(out + b, 2.0f * (red[0] + red[1] + red[2] + red[3]));
}

extern "C" void kernel_launch(void* const* d_in, const int* in_sizes, int n_in,
                              void* d_out, int out_size, void* d_ws, size_t ws_size,
                              hipStream_t stream) {
    const float* z       = (const float*)d_in[0];   // (B,K,H,W) fp32 0/1
    const float* w_logit = (const float*)d_in[1];   // (K,)
    const float* tau     = (const float*)d_in[2];   // scalar
    float* out = (float*)d_out;                     // (B,)
    unsigned* packw = (unsigned*)d_ws;              // 2 MB, word-major

    hipLaunchKernelGGL(pack_kernel, dim3(512), dim3(256), 0, stream,
                       z, packw, out);
    hipLaunchKernelGGL(energy_kernel, dim3(2048), dim3(256), 0, stream,
                       packw, w_logit, tau, out);
}

// Round 7
// 30.138 us; speedup vs baseline: 1.6071x; 1.6071x over previous
//
#include <hip/hip_runtime.h>
#include <math.h>

// LearnedDRoPEEnergy: B=16, K=256, H=W=64, T=1.0
// R7 = R1 config (best measured: 33.6us) with ONE change: 8-offset symmetry.
#define BB   16
#define KK   256
#define HWSZ 4096        // H*W
#define NPOS 65536       // B*H*W
#define NWORDS 8         // K/32

// 8 representative offsets (other 8 are negatives; d and gate symmetric,
// torus sum translation-invariant -> x2). Verified exact R2/R4/R5/R6.
__device__ __constant__ int c_dy8[8] = {-1, 0, -1, -1, -2,  0, -2, -2};
__device__ __constant__ int c_dx8[8] = { 0,-1, -1,  1,  0, -2, -2,  2};

// Kernel A: R1 pack verbatim. One thread per (word, pos); lane-consecutive pos
// -> 256B-coalesced scalar loads per k-plane; dword store at 32B stride.
__global__ __launch_bounds__(256) void pack_kernel(const float* __restrict__ z,
                                                   unsigned* __restrict__ pack,
                                                   float* __restrict__ out) {
    int t = blockIdx.x * 256 + threadIdx.x;      // 0 .. NPOS*NWORDS-1
    int word = t >> 16;                          // NPOS == 1<<16
    int pos  = t & (NPOS - 1);
    int b    = pos >> 12;                        // pos / HWSZ
    int hw   = pos & (HWSZ - 1);
    const float* base = z + (size_t)(b * KK + word * 32) * HWSZ + hw;
    unsigned acc = 0u;
#pragma unroll
    for (int j = 0; j < 32; ++j) {
        float v = base[(size_t)j * HWSZ];
        acc |= (v != 0.0f) ? (1u << j) : 0u;
    }
    pack[pos * NWORDS + word] = acc;
    if (t < BB) out[t] = 0.0f;
}

// Kernel B: R1 energy structure (256 blocks x 256 threads, thread = one pos,
// in-kernel LUT, offset loop in-thread, one atomic per block) with the offset
// loop cut 16 -> 8 via symmetry, result x2.
__global__ __launch_bounds__(256) void energy_kernel(const unsigned* __restrict__ pack,
                                                     const float* __restrict__ w_logit,
                                                     const float* __restrict__ tau_p,
                                                     float* __restrict__ out) {
    __shared__ float wtab[32 * 256];   // 32 KB byte-LUT
    __shared__ float red[4];

    int tid = threadIdx.x;
    {   // build LUT: thread covers (p = tid>>3, v = (tid&7)*32 .. +31)
        int p = tid >> 3;
        int vbase = (tid & 7) * 32;
        float wv[8];
#pragma unroll
        for (int j = 0; j < 8; ++j) {
            float x = w_logit[p * 8 + j];
            wv[j] = log1pf(expf(x));   // softplus, fp32
        }
        for (int v = vbase; v < vbase + 32; ++v) {
            float s = 0.0f;
#pragma unroll
            for (int j = 0; j < 8; ++j) s += ((v >> j) & 1) ? wv[j] : 0.0f;
            wtab[p * 256 + v] = s;
        }
    }
    __syncthreads();

    float tau = tau_p[0];
    int pos = blockIdx.x * 256 + tid;            // one thread per position
    int b = pos >> 12;
    int h = (pos >> 6) & 63;
    int w = pos & 63;

    const uint4* pk = (const uint4*)pack;        // 32 B per position
    uint4 o0 = pk[pos * 2 + 0];
    uint4 o1 = pk[pos * 2 + 1];

    float e = 0.0f;
#pragma unroll
    for (int o = 0; o < 8; ++o) {
        int h2 = (h + c_dy8[o]) & 63;
        int w2 = (w + c_dx8[o]) & 63;
        int np = (b << 12) | (h2 << 6) | w2;
        uint4 n0 = pk[np * 2 + 0];
        uint4 n1 = pk[np * 2 + 1];
        unsigned x[8];
        x[0] = o0.x ^ n0.x; x[1] = o0.y ^ n0.y; x[2] = o0.z ^ n0.z; x[3] = o0.w ^ n0.w;
        x[4] = o1.x ^ n1.x; x[5] = o1.y ^ n1.y; x[6] = o1.z ^ n1.z; x[7] = o1.w ^ n1.w;
        float d0 = 0.0f, d1 = 0.0f;
#pragma unroll
        for (int i = 0; i < 8; ++i) {
            unsigned xi = x[i];
            d0 += wtab[(i * 4 + 0) * 256 + (xi & 255)];
            d1 += wtab[(i * 4 + 1) * 256 + ((xi >> 8) & 255)];
            d0 += wtab[(i * 4 + 2) * 256 + ((xi >> 16) & 255)];
            d1 += wtab[(i * 4 + 3) * 256 + (xi >> 24)];
        }
        float d = d0 + d1;
        // gate*d = d / (1 + exp(d - tau)); exp overflow -> inf -> 0, correct limit
        e += d / (1.0f + expf(d - tau));
    }

    // block reduction: all 256 threads share b; x2 for symmetry
#pragma unroll
    for (int s = 32; s > 0; s >>= 1) e += __shfl_down(e, s, 64);
    int lane = tid & 63, wv = tid >> 6;
    if (lane == 0) red[wv] = e;
    __syncthreads();
    if (tid == 0) {
        float s = red[0] + red[1] + red[2] + red[3];
        atomicAdd(out + b, 2.0f * s);
    }
}

extern "C" void kernel_launch(void* const* d_in, const int* in_sizes, int n_in,
                              void* d_out, int out_size, void* d_ws, size_t ws_size,
                              hipStream_t stream) {
    const float* z       = (const float*)d_in[0];   // (B,K,H,W) fp32 0/1
    const float* w_logit = (const float*)d_in[1];   // (K,)
    const float* tau     = (const float*)d_in[2];   // scalar
    float* out = (float*)d_out;                     // (B,)
    unsigned* pack = (unsigned*)d_ws;               // 2 MB

    hipLaunchKernelGGL(pack_kernel, dim3(NPOS * NWORDS / 256), dim3(256), 0, stream,
                       z, pack, out);
    hipLaunchKernelGGL(energy_kernel, dim3(NPOS / 256), dim3(256), 0, stream,
                       pack, w_logit, tau, out);
}

// Round 8
// 28.715 us; speedup vs baseline: 1.6868x; 1.0495x over previous
//
#include <hip/hip_runtime.h>
#include <math.h>

// LearnedDRoPEEnergy: B=16, K=256, H=W=64, T=1.0
// R8: pack redesigned for fully-SEQUENTIAL per-block HBM sweeps (the 16KB
// power-of-2 plane stride was capping pack at ~2.6 TB/s in R1-R7).
#define NPOS 65536
#define HWSZ 4096

typedef float floatx4 __attribute__((ext_vector_type(4)));

// 8 representative offsets (other 8 are negatives; d and gate symmetric,
// torus sum translation-invariant -> x2). Verified R2/R4/R5/R6/R7.
__device__ __constant__ int c_dy8[8] = {-1, 0, -1, -1, -2,  0, -2, -2};
__device__ __constant__ int c_dx8[8] = { 0,-1, -1,  1,  0, -2, -2,  2};

// Kernel A: pack. Block beta = b*16 + q owns 16 CONSECUTIVE k-planes
// (k = 16q..16q+15) = one unbroken 256 KB region of z (planes are contiguous
// in [b][k][hw] layout: beta*65536 floats). Loop j(outer) i(inner) walks it
// in ascending address order -> pure sequential HBM stream, no 16KB hops.
// Register transpose: thread's 4 positions per i-chunk are fixed across j,
// so 16 u16 accumulators (compile-time indexed) collect bit j.
// Output layout: pack16[g][pos], g = b*16+q (u16 per (g,pos)), 2 MB total.
__global__ __launch_bounds__(256) void pack_kernel(const float* __restrict__ z,
                                                   unsigned* __restrict__ packu32,
                                                   float* __restrict__ out) {
    int tid = threadIdx.x;
    unsigned beta = blockIdx.x;                 // 0..255 = b*16 + q
    const float* base = z + ((size_t)beta << 16);   // beta * 16 * 4096 floats
    unsigned acc[16];                           // [i*4 + c], u16 values
#pragma unroll
    for (int t = 0; t < 16; ++t) acc[t] = 0u;
#pragma unroll
    for (int j = 0; j < 16; ++j) {              // plane within group (bit j)
#pragma unroll
        for (int i = 0; i < 4; ++i) {           // position chunk
            floatx4 v = __builtin_nontemporal_load(
                (const floatx4*)(base + (j << 12) + (i << 10) + (tid << 2)));
            unsigned bit = 1u << j;
            if (v.x != 0.0f) acc[i * 4 + 0] |= bit;
            if (v.y != 0.0f) acc[i * 4 + 1] |= bit;
            if (v.z != 0.0f) acc[i * 4 + 2] |= bit;
            if (v.w != 0.0f) acc[i * 4 + 3] |= bit;
        }
    }
    // store: pos = i*1024 + tid*4 + c; as u32 pairs (c0|c1<<16), (c2|c3<<16)
    unsigned* dst = packu32 + ((size_t)beta << 11);   // beta*4096 u16 = beta*2048 u32
#pragma unroll
    for (int i = 0; i < 4; ++i) {
        unsigned lo = acc[i * 4 + 0] | (acc[i * 4 + 1] << 16);
        unsigned hi = acc[i * 4 + 2] | (acc[i * 4 + 3] << 16);
        *(uint2*)(dst + (i << 9) + (tid << 1)) = make_uint2(lo, hi);  // 8B/lane coalesced
    }
    if (beta == 0 && tid < 16) out[tid] = 0.0f;
}

// Kernel B: R7 energy structure verbatim (256 blocks, thread = one position,
// in-kernel LUT, 8 offsets in-thread, x2 symmetry), loads adapted to the
// q-major u16 layout: 16 coalesced u16 loads per record, all L2-resident.
__global__ __launch_bounds__(256) void energy_kernel(const unsigned short* __restrict__ p16,
                                                     const float* __restrict__ w_logit,
                                                     const float* __restrict__ tau_p,
                                                     float* __restrict__ out) {
    __shared__ float wtab[32 * 256];   // 32 KB byte-LUT: wtab[p][v], p = k/8
    __shared__ float red[4];

    int tid = threadIdx.x;
    {   // build LUT: thread covers (p = tid>>3, v = (tid&7)*32 .. +31)
        int p = tid >> 3;
        int vbase = (tid & 7) * 32;
        float wv[8];
#pragma unroll
        for (int j = 0; j < 8; ++j) {
            float x = w_logit[p * 8 + j];
            wv[j] = log1pf(expf(x));   // softplus, fp32
        }
        for (int v = vbase; v < vbase + 32; ++v) {
            float s = 0.0f;
#pragma unroll
            for (int j = 0; j < 8; ++j) s += ((v >> j) & 1) ? wv[j] : 0.0f;
            wtab[p * 256 + v] = s;
        }
    }
    __syncthreads();

    float tau = tau_p[0];
    int pos = blockIdx.x * 256 + tid;            // one thread per position
    int b  = pos >> 12;
    int hw = pos & 4095;
    int h  = hw >> 6;
    int w  = hw & 63;

    const unsigned short* pb = p16 + ((size_t)b << 16);  // b*16 groups * 4096

    unsigned cw[16];                             // center words, loaded once
#pragma unroll
    for (int q = 0; q < 16; ++q) cw[q] = pb[(q << 12) + hw];

    float e = 0.0f;
#pragma unroll
    for (int o = 0; o < 8; ++o) {
        int h2 = (h + c_dy8[o]) & 63;
        int w2 = (w + c_dx8[o]) & 63;
        int hw2 = (h2 << 6) | w2;
        float d0 = 0.0f, d1 = 0.0f;
#pragma unroll
        for (int q = 0; q < 16; ++q) {
            unsigned x = cw[q] ^ (unsigned)pb[(q << 12) + hw2];  // u16 XOR
            d0 += wtab[(2 * q + 0) * 256 + (x & 255)];
            d1 += wtab[(2 * q + 1) * 256 + (x >> 8)];
        }
        float d = d0 + d1;
        // gate*d = d / (1 + exp(d - tau)); exp overflow -> inf -> 0, correct limit
        e += d / (1.0f + expf(d - tau));
    }

    // block reduction (b uniform per block); x2 for symmetry
#pragma unroll
    for (int s = 32; s > 0; s >>= 1) e += __shfl_down(e, s, 64);
    int lane = tid & 63, wv = tid >> 6;
    if (lane == 0) red[wv] = e;
    __syncthreads();
    if (tid == 0) {
        float s = red[0] + red[1] + red[2] + red[3];
        atomicAdd(out + b, 2.0f * s);
    }
}

extern "C" void kernel_launch(void* const* d_in, const int* in_sizes, int n_in,
                              void* d_out, int out_size, void* d_ws, size_t ws_size,
                              hipStream_t stream) {
    const float* z       = (const float*)d_in[0];   // (B,K,H,W) fp32 0/1
    const float* w_logit = (const float*)d_in[1];   // (K,)
    const float* tau     = (const float*)d_in[2];   // scalar
    float* out = (float*)d_out;                     // (B,)
    unsigned* packu32 = (unsigned*)d_ws;            // 2 MB, q-major u16 layout

    hipLaunchKernelGGL(pack_kernel, dim3(256), dim3(256), 0, stream,
                       z, packu32, out);
    hipLaunchKernelGGL(energy_kernel, dim3(256), dim3(256), 0, stream,
                       (const unsigned short*)packu32, w_logit, tau, out);
}